// Round 1
// baseline (626.011 us; speedup 1.0000x reference)
//
#include <hip/hip_runtime.h>
#include <hip/hip_bf16.h>
#include <stdint.h>

#define B_ 2
#define S_ 2048
#define D_ 2048
#define H_ 32
#define KV_ 8
#define HD_ 64
#define NQKV 3072   // D + 2*KV*HD

typedef __bf16 bf16_t;
typedef __bf16 bf16x8 __attribute__((ext_vector_type(8)));
typedef __bf16 bf16x4 __attribute__((ext_vector_type(4)));
typedef float  f32x4  __attribute__((ext_vector_type(4)));

typedef const __attribute__((address_space(1))) uint32_t* gp1_t;
typedef __attribute__((address_space(3))) uint32_t* lp3_t;

// async global->LDS, 16B per lane. LDS dest is wave-uniform base + lane*16.
__device__ inline void gload_lds16(const void* g, void* l) {
  __builtin_amdgcn_global_load_lds((gp1_t)(uintptr_t)g, (lp3_t)(uint32_t)(uintptr_t)l,
                                   16, 0, 0);
}

// ---------------- converts ----------------
__global__ void cvt_f32_bf16(const float* __restrict__ in, bf16_t* __restrict__ out, int n4) {
  int i = blockIdx.x * blockDim.x + threadIdx.x;
  if (i < n4) {
    float4 v = ((const float4*)in)[i];
    bf16x4 o;
    o[0] = (bf16_t)v.x; o[1] = (bf16_t)v.y; o[2] = (bf16_t)v.z; o[3] = (bf16_t)v.w;
    ((bf16x4*)out)[i] = o;
  }
}

// in: R(=2048) x C f32  ->  out rows [row_off, row_off+C) of a (? x 2048) bf16 matrix,
// out[row_off + c][r] = in[r][c]   (i.e. transpose + cast)
__global__ void transpose_cvt(const float* __restrict__ in, bf16_t* __restrict__ out,
                              int C, int row_off) {
  __shared__ float t[32][33];
  int tx = threadIdx.x, ty = threadIdx.y;       // (32,8)
  int c0 = blockIdx.x * 32, r0 = blockIdx.y * 32;
#pragma unroll
  for (int j = 0; j < 4; ++j)
    t[ty + j*8][tx] = in[(int64_t)(r0 + ty + j*8) * C + c0 + tx];
  __syncthreads();
#pragma unroll
  for (int j = 0; j < 4; ++j)
    out[(int64_t)(row_off + c0 + ty + j*8) * 2048 + r0 + tx] = (bf16_t)t[tx][ty + j*8];
}

// ---------------- GEMM: C = A @ B, with Bt = B^T (N x K) ----------------
// A: M x K bf16 row-major. Bt: N x K bf16 row-major. C: M x N (OutT).
// 128x128 tile, BK=32, 256 threads (4 waves, 2x2 of 64x64), 16x16x32 MFMA.
template <typename OutT>
__global__ __launch_bounds__(256) void gemm_bt(const bf16_t* __restrict__ A,
                                               const bf16_t* __restrict__ Bt,
                                               OutT* __restrict__ C,
                                               int M, int N, int K) {
  __shared__ bf16_t As[128 * 32];
  __shared__ bf16_t Bs[128 * 32];
  const int tid = threadIdx.x;
  const int wid = tid >> 6, lane = tid & 63;
  const int l15 = lane & 15, l4 = lane >> 4;
  const int bm = blockIdx.y * 128, bn = blockIdx.x * 128;
  const int wm = (wid >> 1) * 64, wn = (wid & 1) * 64;

  f32x4 acc[4][4] = {};

  // staging map: slot s = i*256 + tid  ->  row = s>>2, k8 = (s&3)*8, LDS byte off = s*16
  const int arow0 = tid >> 2;
  const int kslot = (tid & 3) * 8;
  const bf16_t* Ag0 = A  + (int64_t)(bm + arow0)      * K + kslot;
  const bf16_t* Ag1 = A  + (int64_t)(bm + arow0 + 64) * K + kslot;
  const bf16_t* Bg0 = Bt + (int64_t)(bn + arow0)      * K + kslot;
  const bf16_t* Bg1 = Bt + (int64_t)(bn + arow0 + 64) * K + kslot;
  char* AsB = (char*)As + wid * 1024;   // wave-uniform LDS bases
  char* BsB = (char*)Bs + wid * 1024;

  for (int k0 = 0; k0 < K; k0 += 32) {
    gload_lds16(Ag0 + k0, AsB);
    gload_lds16(Ag1 + k0, AsB + 4096);
    gload_lds16(Bg0 + k0, BsB);
    gload_lds16(Bg1 + k0, BsB + 4096);
    asm volatile("s_waitcnt vmcnt(0)" ::: "memory");
    __syncthreads();

    bf16x8 af[4], bf[4];
#pragma unroll
    for (int m = 0; m < 4; ++m)
      af[m] = *(const bf16x8*)(As + (wm + m*16 + l15) * 32 + l4 * 8);
#pragma unroll
    for (int n = 0; n < 4; ++n)
      bf[n] = *(const bf16x8*)(Bs + (wn + n*16 + l15) * 32 + l4 * 8);
#pragma unroll
    for (int m = 0; m < 4; ++m)
#pragma unroll
      for (int n = 0; n < 4; ++n)
        acc[m][n] = __builtin_amdgcn_mfma_f32_16x16x32_bf16(af[m], bf[n], acc[m][n], 0, 0, 0);
    __syncthreads();
  }

#pragma unroll
  for (int m = 0; m < 4; ++m) {
    const int row = bm + wm + m*16 + l4*4;
#pragma unroll
    for (int n = 0; n < 4; ++n) {
      const int col = bn + wn + n*16 + l15;
#pragma unroll
      for (int r = 0; r < 4; ++r)
        C[(int64_t)(row + r) * N + col] = (OutT)acc[m][n][r];
    }
  }
}

// ---------------- RoPE + scatter into attention layouts ----------------
// qkv: (B*S, 3072) bf16. Writes Q (B,H,S,HD), K (B,KV,S,HD) with RoPE; V^T (B,KV,HD,S).
__global__ void rope_scatter(const bf16_t* __restrict__ qkv,
                             const float* __restrict__ cosb, const float* __restrict__ sinb,
                             bf16_t* __restrict__ Q, bf16_t* __restrict__ Kr,
                             bf16_t* __restrict__ Vt) {
  const int row = blockIdx.x;            // b*S + s
  const int b = row / S_, s = row % S_;
  const bf16_t* src = qkv + (int64_t)row * NQKV;
  const float* cs = cosb + s * HD_;
  const float* sn = sinb + s * HD_;
  for (int c = threadIdx.x; c < NQKV; c += 256) {
    if (c < D_) {                        // Q
      int h = c >> 6, d = c & 63;
      float v = (float)src[c];
      float p = (d < 32) ? -(float)src[c + 32] : (float)src[c - 32];
      float o = v * cs[d] + p * sn[d];
      Q[((int64_t)(b * H_ + h) * S_ + s) * HD_ + d] = (bf16_t)o;
    } else if (c < D_ + KV_ * HD_) {     // K
      int cc = c - D_;
      int kvh = cc >> 6, d = cc & 63;
      float v = (float)src[c];
      float p = (d < 32) ? -(float)src[c + 32] : (float)src[c - 32];
      float o = v * cs[d] + p * sn[d];
      Kr[((int64_t)(b * KV_ + kvh) * S_ + s) * HD_ + d] = (bf16_t)o;
    } else {                             // V (transposed)
      int cc = c - D_ - KV_ * HD_;
      int kvh = cc >> 6, d = cc & 63;
      Vt[((int64_t)(b * KV_ + kvh) * HD_ + d) * S_ + s] = src[c];
    }
  }
}

// ---------------- flash attention (causal, GQA) ----------------
// grid (S/64, H, B), 256 threads = 4 waves, each wave owns 16 q-rows.
__global__ __launch_bounds__(256) void attn(const bf16_t* __restrict__ Q,
                                            const bf16_t* __restrict__ Kr,
                                            const bf16_t* __restrict__ Vt,
                                            bf16_t* __restrict__ AO) {
  const int qb = blockIdx.x, h = blockIdx.y, b = blockIdx.z;
  const int kvh = h >> 2;                 // NREP = 4
  const int tid = threadIdx.x, wid = tid >> 6, lane = tid & 63;
  const int l15 = lane & 15, l4 = lane >> 4;
  const int q0w = qb * 64 + wid * 16;

  const bf16_t* Qb = Q  + ((int64_t)(b * H_ + h) * S_ + q0w) * HD_;
  const bf16_t* Kb = Kr + (int64_t)(b * KV_ + kvh) * S_ * HD_;
  const bf16_t* Vb = Vt + (int64_t)(b * KV_ + kvh) * HD_ * S_;

  __shared__ bf16_t Pl[4][16][64];        // per-wave P tile

  bf16x8 qf[2];
  qf[0] = *(const bf16x8*)(Qb + l15 * HD_ + l4 * 8);
  qf[1] = *(const bf16x8*)(Qb + l15 * HD_ + 32 + l4 * 8);

  float mrun[4] = {-3e38f, -3e38f, -3e38f, -3e38f};
  float lrun[4] = {0.f, 0.f, 0.f, 0.f};
  f32x4 oacc[4] = {};                     // [vn][reg]

  for (int t = 0; t <= qb; ++t) {
    const int kv0 = t * 64;
    f32x4 sf[4] = {};
#pragma unroll
    for (int n = 0; n < 4; ++n) {
      const bf16_t* Kp = Kb + (int64_t)(kv0 + n*16 + l15) * HD_ + l4 * 8;
      bf16x8 k0 = *(const bf16x8*)(Kp);
      bf16x8 k1 = *(const bf16x8*)(Kp + 32);
      sf[n] = __builtin_amdgcn_mfma_f32_16x16x32_bf16(qf[0], k0, sf[n], 0, 0, 0);
      sf[n] = __builtin_amdgcn_mfma_f32_16x16x32_bf16(qf[1], k1, sf[n], 0, 0, 0);
    }
    const bool diag = (t == qb);
    float pv[4][4];
#pragma unroll
    for (int n = 0; n < 4; ++n)
#pragma unroll
      for (int r = 0; r < 4; ++r) {
        float sc = sf[n][r] * 0.125f;
        if (diag && (n*16 + l15) > (wid*16 + l4*4 + r)) sc = -1e30f;
        pv[n][r] = sc;
      }
    float mnew[4], esc[4], psum[4];
#pragma unroll
    for (int r = 0; r < 4; ++r) {
      float m = fmaxf(fmaxf(pv[0][r], pv[1][r]), fmaxf(pv[2][r], pv[3][r]));
      m = fmaxf(m, __shfl_xor(m, 1));
      m = fmaxf(m, __shfl_xor(m, 2));
      m = fmaxf(m, __shfl_xor(m, 4));
      m = fmaxf(m, __shfl_xor(m, 8));
      mnew[r] = fmaxf(mrun[r], m);
      esc[r] = __expf(mrun[r] - mnew[r]);
      mrun[r] = mnew[r];
      psum[r] = 0.f;
    }
#pragma unroll
    for (int n = 0; n < 4; ++n)
#pragma unroll
      for (int r = 0; r < 4; ++r) {
        float p = __expf(pv[n][r] - mnew[r]);
        psum[r] += p;
        Pl[wid][l4*4 + r][n*16 + l15] = (bf16_t)p;
      }
#pragma unroll
    for (int r = 0; r < 4; ++r) {
      float ps = psum[r];
      ps += __shfl_xor(ps, 1);
      ps += __shfl_xor(ps, 2);
      ps += __shfl_xor(ps, 4);
      ps += __shfl_xor(ps, 8);
      lrun[r] = lrun[r] * esc[r] + ps;
#pragma unroll
      for (int vn = 0; vn < 4; ++vn) oacc[vn][r] *= esc[r];
    }
    // wave-local LDS write->read ordering
    asm volatile("s_waitcnt lgkmcnt(0)" ::: "memory");
    bf16x8 pa0 = *(const bf16x8*)(&Pl[wid][l15][l4 * 8]);
    bf16x8 pa1 = *(const bf16x8*)(&Pl[wid][l15][32 + l4 * 8]);
#pragma unroll
    for (int vn = 0; vn < 4; ++vn) {
      const bf16_t* Vp = Vb + (int64_t)(vn*16 + l15) * S_ + kv0 + l4 * 8;
      bf16x8 v0 = *(const bf16x8*)(Vp);
      bf16x8 v1 = *(const bf16x8*)(Vp + 32);
      oacc[vn] = __builtin_amdgcn_mfma_f32_16x16x32_bf16(pa0, v0, oacc[vn], 0, 0, 0);
      oacc[vn] = __builtin_amdgcn_mfma_f32_16x16x32_bf16(pa1, v1, oacc[vn], 0, 0, 0);
    }
  }
  // epilogue: AO (B, S, H*HD)
#pragma unroll
  for (int vn = 0; vn < 4; ++vn)
#pragma unroll
    for (int r = 0; r < 4; ++r) {
      const int64_t row = (int64_t)(b * S_ + q0w + l4*4 + r);
      AO[row * D_ + h * HD_ + vn*16 + l15] = (bf16_t)(oacc[vn][r] / lrun[r]);
    }
}

// ---------------- launcher ----------------
extern "C" void kernel_launch(void* const* d_in, const int* in_sizes, int n_in,
                              void* d_out, int out_size, void* d_ws, size_t ws_size,
                              hipStream_t stream) {
  const float* x    = (const float*)d_in[0];
  const float* cosb = (const float*)d_in[1];
  const float* sinb = (const float*)d_in[2];
  const float* Wq   = (const float*)d_in[3];
  const float* Wk   = (const float*)d_in[4];
  const float* Wv   = (const float*)d_in[5];
  const float* Wo   = (const float*)d_in[6];
  float* out = (float*)d_out;

  bf16_t* ws = (bf16_t*)d_ws;
  size_t o = 0;
  bf16_t* xb    = ws + o; o += (size_t)4096 * 2048;
  bf16_t* Wqkvt = ws + o; o += (size_t)3072 * 2048;
  bf16_t* Wot   = ws + o; o += (size_t)2048 * 2048;
  bf16_t* qkv   = ws + o; o += (size_t)4096 * 3072;
  bf16_t* Qr    = ws + o; o += (size_t)B_ * H_ * S_ * HD_;
  bf16_t* Krb   = ws + o; o += (size_t)B_ * KV_ * S_ * HD_;
  bf16_t* Vtb   = ws + o; o += (size_t)B_ * KV_ * S_ * HD_;
  bf16_t* AO    = ws + o; o += (size_t)4096 * 2048;
  // total ~105 MB of d_ws

  // x -> bf16
  cvt_f32_bf16<<<(8388608/4 + 255)/256, 256, 0, stream>>>(x, xb, 8388608/4);
  // weights -> bf16, transposed (N x K)
  transpose_cvt<<<dim3(2048/32, 2048/32), dim3(32, 8), 0, stream>>>(Wq, Wqkvt, 2048, 0);
  transpose_cvt<<<dim3(512/32, 2048/32),  dim3(32, 8), 0, stream>>>(Wk, Wqkvt, 512, 2048);
  transpose_cvt<<<dim3(512/32, 2048/32),  dim3(32, 8), 0, stream>>>(Wv, Wqkvt, 512, 2560);
  transpose_cvt<<<dim3(2048/32, 2048/32), dim3(32, 8), 0, stream>>>(Wo, Wot, 2048, 0);
  // fused QKV projection: (4096 x 2048) @ (2048 x 3072) -> bf16
  gemm_bt<bf16_t><<<dim3(3072/128, 4096/128), 256, 0, stream>>>(xb, Wqkvt, qkv, 4096, 3072, 2048);
  // RoPE + scatter
  rope_scatter<<<4096, 256, 0, stream>>>(qkv, cosb, sinb, Qr, Krb, Vtb);
  // causal GQA attention
  attn<<<dim3(S_/64, H_, B_), 256, 0, stream>>>(Qr, Krb, Vtb, AO);
  // output projection -> f32
  gemm_bt<float><<<dim3(2048/128, 4096/128), 256, 0, stream>>>(AO, Wot, out, 4096, 2048, 2048);
}

// Round 2
// 341.850 us; speedup vs baseline: 1.8312x; 1.8312x over previous
//
#include <hip/hip_runtime.h>
#include <hip/hip_bf16.h>
#include <stdint.h>

#define B_ 2
#define S_ 2048
#define D_ 2048
#define H_ 32
#define KV_ 8
#define HD_ 64
#define NQKV 3072   // D + 2*KV*HD

typedef __bf16 bf16_t;
typedef __bf16 bf16x8 __attribute__((ext_vector_type(8)));
typedef __bf16 bf16x4 __attribute__((ext_vector_type(4)));
typedef float  f32x4  __attribute__((ext_vector_type(4)));
typedef float  f32x16 __attribute__((ext_vector_type(16)));
typedef unsigned int u32;
typedef u32 u32x4 __attribute__((ext_vector_type(4)));

typedef const __attribute__((address_space(1))) uint32_t* gp1_t;
typedef __attribute__((address_space(3))) uint32_t* lp3_t;

// async global->LDS, 16B per lane. LDS dest is wave-uniform base + lane*16.
__device__ inline void gload_lds16(const void* g, void* l) {
  __builtin_amdgcn_global_load_lds((gp1_t)(uintptr_t)g, (lp3_t)(uint32_t)(uintptr_t)l,
                                   16, 0, 0);
}

__device__ inline u32 pkbf(float a, float b) {
  union { bf16_t h[2]; u32 u; } v;
  v.h[0] = (bf16_t)a; v.h[1] = (bf16_t)b;
  return v.u;
}

// ---------------- converts ----------------
__global__ void cvt_f32_bf16(const float* __restrict__ in, bf16_t* __restrict__ out, int n4) {
  int i = blockIdx.x * blockDim.x + threadIdx.x;
  if (i < n4) {
    float4 v = ((const float4*)in)[i];
    bf16x4 o;
    o[0] = (bf16_t)v.x; o[1] = (bf16_t)v.y; o[2] = (bf16_t)v.z; o[3] = (bf16_t)v.w;
    ((bf16x4*)out)[i] = o;
  }
}

// transpose + cast: out[row_off + c][r] = in[r][c]
__global__ void transpose_cvt(const float* __restrict__ in, bf16_t* __restrict__ out,
                              int C, int row_off) {
  __shared__ float t[32][33];
  int tx = threadIdx.x, ty = threadIdx.y;       // (32,8)
  int c0 = blockIdx.x * 32, r0 = blockIdx.y * 32;
#pragma unroll
  for (int j = 0; j < 4; ++j)
    t[ty + j*8][tx] = in[(int64_t)(r0 + ty + j*8) * C + c0 + tx];
  __syncthreads();
#pragma unroll
  for (int j = 0; j < 4; ++j)
    out[(int64_t)(row_off + c0 + ty + j*8) * 2048 + r0 + tx] = (bf16_t)t[tx][ty + j*8];
}

// ---------------- GEMM: C = A @ B, with Bt = B^T (N x K) ----------------
template <typename OutT>
__global__ __launch_bounds__(256) void gemm_bt(const bf16_t* __restrict__ A,
                                               const bf16_t* __restrict__ Bt,
                                               OutT* __restrict__ C,
                                               int M, int N, int K) {
  __shared__ bf16_t As[128 * 32];
  __shared__ bf16_t Bs[128 * 32];
  const int tid = threadIdx.x;
  const int wid = tid >> 6, lane = tid & 63;
  const int l15 = lane & 15, l4 = lane >> 4;
  const int bm = blockIdx.y * 128, bn = blockIdx.x * 128;
  const int wm = (wid >> 1) * 64, wn = (wid & 1) * 64;

  f32x4 acc[4][4] = {};

  const int arow0 = tid >> 2;
  const int kslot = (tid & 3) * 8;
  const bf16_t* Ag0 = A  + (int64_t)(bm + arow0)      * K + kslot;
  const bf16_t* Ag1 = A  + (int64_t)(bm + arow0 + 64) * K + kslot;
  const bf16_t* Bg0 = Bt + (int64_t)(bn + arow0)      * K + kslot;
  const bf16_t* Bg1 = Bt + (int64_t)(bn + arow0 + 64) * K + kslot;
  char* AsB = (char*)As + wid * 1024;
  char* BsB = (char*)Bs + wid * 1024;

  for (int k0 = 0; k0 < K; k0 += 32) {
    gload_lds16(Ag0 + k0, AsB);
    gload_lds16(Ag1 + k0, AsB + 4096);
    gload_lds16(Bg0 + k0, BsB);
    gload_lds16(Bg1 + k0, BsB + 4096);
    asm volatile("s_waitcnt vmcnt(0)" ::: "memory");
    __syncthreads();

    bf16x8 af[4], bfr[4];
#pragma unroll
    for (int m = 0; m < 4; ++m)
      af[m] = *(const bf16x8*)(As + (wm + m*16 + l15) * 32 + l4 * 8);
#pragma unroll
    for (int n = 0; n < 4; ++n)
      bfr[n] = *(const bf16x8*)(Bs + (wn + n*16 + l15) * 32 + l4 * 8);
#pragma unroll
    for (int m = 0; m < 4; ++m)
#pragma unroll
      for (int n = 0; n < 4; ++n)
        acc[m][n] = __builtin_amdgcn_mfma_f32_16x16x32_bf16(af[m], bfr[n], acc[m][n], 0, 0, 0);
    __syncthreads();
  }

#pragma unroll
  for (int m = 0; m < 4; ++m) {
    const int row = bm + wm + m*16 + l4*4;
#pragma unroll
    for (int n = 0; n < 4; ++n) {
      const int col = bn + wn + n*16 + l15;
#pragma unroll
      for (int r = 0; r < 4; ++r)
        C[(int64_t)(row + r) * N + col] = (OutT)acc[m][n][r];
    }
  }
}

// ---------------- RoPE + scatter ----------------
// Q is pre-scaled by 0.125 * log2(e) so attention can use exp2.
#define QSCALE 0.18033688011112042f
__global__ void rope_scatter(const bf16_t* __restrict__ qkv,
                             const float* __restrict__ cosb, const float* __restrict__ sinb,
                             bf16_t* __restrict__ Q, bf16_t* __restrict__ Kr,
                             bf16_t* __restrict__ Vt) {
  const int row = blockIdx.x;            // b*S + s
  const int b = row / S_, s = row % S_;
  const bf16_t* src = qkv + (int64_t)row * NQKV;
  const float* cs = cosb + s * HD_;
  const float* sn = sinb + s * HD_;
  for (int c = threadIdx.x; c < NQKV; c += 256) {
    if (c < D_) {                        // Q (scaled)
      int h = c >> 6, d = c & 63;
      float v = (float)src[c];
      float p = (d < 32) ? -(float)src[c + 32] : (float)src[c - 32];
      float o = (v * cs[d] + p * sn[d]) * QSCALE;
      Q[((int64_t)(b * H_ + h) * S_ + s) * HD_ + d] = (bf16_t)o;
    } else if (c < D_ + KV_ * HD_) {     // K
      int cc = c - D_;
      int kvh = cc >> 6, d = cc & 63;
      float v = (float)src[c];
      float p = (d < 32) ? -(float)src[c + 32] : (float)src[c - 32];
      float o = v * cs[d] + p * sn[d];
      Kr[((int64_t)(b * KV_ + kvh) * S_ + s) * HD_ + d] = (bf16_t)o;
    } else {                             // V (transposed: [d][s])
      int cc = c - D_ - KV_ * HD_;
      int kvh = cc >> 6, d = cc & 63;
      Vt[((int64_t)(b * KV_ + kvh) * HD_ + d) * S_ + s] = src[c];
    }
  }
}

// ---------------- flash attention, swapped-operand 32x32 MFMA ----------------
// grid (64 = h + 32*b, 16 = qchunk), 256 threads = 4 waves, wave owns 32 q-rows.
// All softmax state is lane-local (lane&31 == q-row). No LDS, no barriers.
__global__ __launch_bounds__(256) void attn2(const bf16_t* __restrict__ Q,
                                             const bf16_t* __restrict__ Kr,
                                             const bf16_t* __restrict__ Vt,
                                             bf16_t* __restrict__ AO) {
  const int hb = blockIdx.x;
  const int h = hb & 31, b = hb >> 5;
  const int qc = blockIdx.y;
  const int tid = threadIdx.x;
  const int w = tid >> 6, lane = tid & 63;
  const int l31 = lane & 31, hi = lane >> 5;
  const int kvh = h >> 2;                 // NREP = 4
  const int q0w = qc * 128 + w * 32;

  const bf16_t* Qb = Q  + ((int64_t)(b * H_ + h) * S_ + q0w) * HD_;
  const bf16_t* Kb = Kr + (int64_t)(b * KV_ + kvh) * S_ * HD_;
  const bf16_t* Vb = Vt + (int64_t)(b * KV_ + kvh) * HD_ * S_;

  // Q fragments (B-operand): lane holds Q[q = q0w+l31][d = ds*16 + hi*8 + j]
  bf16x8 qf[4];
#pragma unroll
  for (int ds = 0; ds < 4; ++ds)
    qf[ds] = *(const bf16x8*)(Qb + l31 * HD_ + ds * 16 + hi * 8);

  f32x16 accO0 = {}, accO1 = {};          // O^T: rows d (0-31 / 32-63), col q = l31
  float mrun = -3e38f, lrun = 0.f;

  const int ND = q0w >> 5;                // tiles 0..ND-1 unmasked, tile ND diagonal
  for (int t = 0; t <= ND; ++t) {
    const int kv0 = t * 32;
    const bool diag = (t == ND);

    // S^T[kv][q] = K . Q^T : lane(q=l31,hi) holds S[kv=(r&3)+8*(r>>2)+4*hi][q]
    f32x16 sacc = {};
#pragma unroll
    for (int ds = 0; ds < 4; ++ds) {
      bf16x8 kf = *(const bf16x8*)(Kb + (int64_t)(kv0 + l31) * HD_ + ds * 16 + hi * 8);
      sacc = __builtin_amdgcn_mfma_f32_32x32x16_bf16(kf, qf[ds], sacc, 0, 0, 0);
    }

    float p[16];
#pragma unroll
    for (int r = 0; r < 16; ++r) {
      float sc = sacc[r];
      if (diag) {
        int kvpos = (r & 3) + 8 * (r >> 2) + 4 * hi;
        if (kvpos > l31) sc = -1e30f;
      }
      p[r] = sc;
    }
    // row max: in-lane 16 + partner half
    float mt = p[0];
#pragma unroll
    for (int r = 1; r < 16; ++r) mt = fmaxf(mt, p[r]);
    mt = fmaxf(mt, __shfl_xor(mt, 32));
    const float mnew = fmaxf(mrun, mt);
    const float esc = exp2f(mrun - mnew);
    mrun = mnew;
    float ts = 0.f;
#pragma unroll
    for (int r = 0; r < 16; ++r) { p[r] = exp2f(p[r] - mnew); ts += p[r]; }
    ts += __shfl_xor(ts, 32);
    lrun = lrun * esc + ts;
#pragma unroll
    for (int r = 0; r < 16; ++r) { accO0[r] *= esc; accO1[r] *= esc; }

    // P -> bf16 fragments (B-operand of PV): lane needs P[q][kv = s*16 + hi*8 + j]
    u32 pk[8], sh[8];
#pragma unroll
    for (int i = 0; i < 8; ++i) pk[i] = pkbf(p[2*i], p[2*i+1]);
#pragma unroll
    for (int i = 0; i < 8; ++i) sh[i] = __shfl_xor(pk[i], 32);
    u32x4 w0, w1;
    if (hi == 0) {
      w0 = (u32x4){pk[0], pk[1], sh[0], sh[1]};
      w1 = (u32x4){pk[4], pk[5], sh[4], sh[5]};
    } else {
      w0 = (u32x4){sh[2], sh[3], pk[2], pk[3]};
      w1 = (u32x4){sh[6], sh[7], pk[6], pk[7]};
    }
    bf16x8 pf0 = __builtin_bit_cast(bf16x8, w0);
    bf16x8 pf1 = __builtin_bit_cast(bf16x8, w1);

    // O^T += V^T . P : A = V^T frag (lane: Vt[d = dt*32+l31][kv0 + s*16 + hi*8 + j])
#pragma unroll
    for (int s2 = 0; s2 < 2; ++s2) {
      bf16x8 pf = s2 ? pf1 : pf0;
      bf16x8 v0 = *(const bf16x8*)(Vb + (int64_t)l31 * S_ + kv0 + s2 * 16 + hi * 8);
      bf16x8 v1 = *(const bf16x8*)(Vb + (int64_t)(32 + l31) * S_ + kv0 + s2 * 16 + hi * 8);
      accO0 = __builtin_amdgcn_mfma_f32_32x32x16_bf16(v0, pf, accO0, 0, 0, 0);
      accO1 = __builtin_amdgcn_mfma_f32_32x32x16_bf16(v1, pf, accO1, 0, 0, 0);
    }
  }

  // epilogue: lane(q=l31) holds O[q][d], d = dt*32 + (r&3) + 8*(r>>2) + 4*hi
  const float rl = 1.f / lrun;
  const int64_t row = (int64_t)(b * S_ + q0w + l31);
#pragma unroll
  for (int dt = 0; dt < 2; ++dt) {
#pragma unroll
    for (int g = 0; g < 4; ++g) {
      bf16x4 ov;
#pragma unroll
      for (int j = 0; j < 4; ++j) {
        float val = (dt ? accO1[4*g + j] : accO0[4*g + j]) * rl;
        ov[j] = (bf16_t)val;
      }
      const int d0 = dt * 32 + g * 8 + hi * 4;
      *(bf16x4*)(AO + row * D_ + h * HD_ + d0) = ov;
    }
  }
}

// ---------------- launcher ----------------
extern "C" void kernel_launch(void* const* d_in, const int* in_sizes, int n_in,
                              void* d_out, int out_size, void* d_ws, size_t ws_size,
                              hipStream_t stream) {
  const float* x    = (const float*)d_in[0];
  const float* cosb = (const float*)d_in[1];
  const float* sinb = (const float*)d_in[2];
  const float* Wq   = (const float*)d_in[3];
  const float* Wk   = (const float*)d_in[4];
  const float* Wv   = (const float*)d_in[5];
  const float* Wo   = (const float*)d_in[6];
  float* out = (float*)d_out;

  bf16_t* ws = (bf16_t*)d_ws;
  size_t o = 0;
  bf16_t* xb    = ws + o; o += (size_t)4096 * 2048;
  bf16_t* Wqkvt = ws + o; o += (size_t)3072 * 2048;
  bf16_t* Wot   = ws + o; o += (size_t)2048 * 2048;
  bf16_t* qkv   = ws + o; o += (size_t)4096 * 3072;
  bf16_t* Qr    = ws + o; o += (size_t)B_ * H_ * S_ * HD_;
  bf16_t* Krb   = ws + o; o += (size_t)B_ * KV_ * S_ * HD_;
  bf16_t* Vtb   = ws + o; o += (size_t)B_ * KV_ * S_ * HD_;
  bf16_t* AO    = ws + o; o += (size_t)4096 * 2048;

  cvt_f32_bf16<<<(8388608/4 + 255)/256, 256, 0, stream>>>(x, xb, 8388608/4);
  transpose_cvt<<<dim3(2048/32, 2048/32), dim3(32, 8), 0, stream>>>(Wq, Wqkvt, 2048, 0);
  transpose_cvt<<<dim3(512/32, 2048/32),  dim3(32, 8), 0, stream>>>(Wk, Wqkvt, 512, 2048);
  transpose_cvt<<<dim3(512/32, 2048/32),  dim3(32, 8), 0, stream>>>(Wv, Wqkvt, 512, 2560);
  transpose_cvt<<<dim3(2048/32, 2048/32), dim3(32, 8), 0, stream>>>(Wo, Wot, 2048, 0);
  gemm_bt<bf16_t><<<dim3(3072/128, 4096/128), 256, 0, stream>>>(xb, Wqkvt, qkv, 4096, 3072, 2048);
  rope_scatter<<<4096, 256, 0, stream>>>(qkv, cosb, sinb, Qr, Krb, Vtb);
  attn2<<<dim3(64, 16), 256, 0, stream>>>(Qr, Krb, Vtb, AO);
  gemm_bt<float><<<dim3(2048/128, 4096/128), 256, 0, stream>>>(AO, Wot, out, 4096, 2048, 2048);
}

// Round 3
// 306.817 us; speedup vs baseline: 2.0403x; 1.1142x over previous
//
#include <hip/hip_runtime.h>
#include <hip/hip_bf16.h>
#include <stdint.h>

#define B_ 2
#define S_ 2048
#define D_ 2048
#define H_ 32
#define KV_ 8
#define HD_ 64
#define NQKV 3072   // D + 2*KV*HD

typedef __bf16 bf16_t;
typedef __bf16 bf16x8 __attribute__((ext_vector_type(8)));
typedef __bf16 bf16x4 __attribute__((ext_vector_type(4)));
typedef float  f32x4  __attribute__((ext_vector_type(4)));
typedef float  f32x16 __attribute__((ext_vector_type(16)));
typedef unsigned int u32;
typedef u32 u32x4 __attribute__((ext_vector_type(4)));

typedef const __attribute__((address_space(1))) uint32_t* gp1_t;
typedef __attribute__((address_space(3))) uint32_t* lp3_t;

// async global->LDS, 16B per lane. LDS dest is wave-uniform base + lane*16.
__device__ inline void gload_lds16(const void* g, void* l) {
  __builtin_amdgcn_global_load_lds((gp1_t)(uintptr_t)g, (lp3_t)(uint32_t)(uintptr_t)l,
                                   16, 0, 0);
}

__device__ inline u32 pkbf(float a, float b) {
  union { bf16_t h[2]; u32 u; } v;
  v.h[0] = (bf16_t)a; v.h[1] = (bf16_t)b;
  return v.u;
}

// ---------------- converts ----------------
__global__ void cvt_f32_bf16(const float* __restrict__ in, bf16_t* __restrict__ out, int n4) {
  int i = blockIdx.x * blockDim.x + threadIdx.x;
  if (i < n4) {
    float4 v = ((const float4*)in)[i];
    bf16x4 o;
    o[0] = (bf16_t)v.x; o[1] = (bf16_t)v.y; o[2] = (bf16_t)v.z; o[3] = (bf16_t)v.w;
    ((bf16x4*)out)[i] = o;
  }
}

// transpose + cast: out[row_off + c][r] = in[r][c]
__global__ void transpose_cvt(const float* __restrict__ in, bf16_t* __restrict__ out,
                              int C, int row_off) {
  __shared__ float t[32][33];
  int tx = threadIdx.x, ty = threadIdx.y;       // (32,8)
  int c0 = blockIdx.x * 32, r0 = blockIdx.y * 32;
#pragma unroll
  for (int j = 0; j < 4; ++j)
    t[ty + j*8][tx] = in[(int64_t)(r0 + ty + j*8) * C + c0 + tx];
  __syncthreads();
#pragma unroll
  for (int j = 0; j < 4; ++j)
    out[(int64_t)(row_off + c0 + ty + j*8) * 2048 + r0 + tx] = (bf16_t)t[tx][ty + j*8];
}

// ---------------- GEMM: C = A @ B, with Bt = B^T (N x K) ----------------
template <typename OutT>
__global__ __launch_bounds__(256) void gemm_bt(const bf16_t* __restrict__ A,
                                               const bf16_t* __restrict__ Bt,
                                               OutT* __restrict__ C,
                                               int M, int N, int K) {
  __shared__ bf16_t As[128 * 32];
  __shared__ bf16_t Bs[128 * 32];
  const int tid = threadIdx.x;
  const int wid = tid >> 6, lane = tid & 63;
  const int l15 = lane & 15, l4 = lane >> 4;
  const int bm = blockIdx.y * 128, bn = blockIdx.x * 128;
  const int wm = (wid >> 1) * 64, wn = (wid & 1) * 64;

  f32x4 acc[4][4] = {};

  const int arow0 = tid >> 2;
  const int kslot = (tid & 3) * 8;
  const bf16_t* Ag0 = A  + (int64_t)(bm + arow0)      * K + kslot;
  const bf16_t* Ag1 = A  + (int64_t)(bm + arow0 + 64) * K + kslot;
  const bf16_t* Bg0 = Bt + (int64_t)(bn + arow0)      * K + kslot;
  const bf16_t* Bg1 = Bt + (int64_t)(bn + arow0 + 64) * K + kslot;
  char* AsB = (char*)As + wid * 1024;
  char* BsB = (char*)Bs + wid * 1024;

  for (int k0 = 0; k0 < K; k0 += 32) {
    gload_lds16(Ag0 + k0, AsB);
    gload_lds16(Ag1 + k0, AsB + 4096);
    gload_lds16(Bg0 + k0, BsB);
    gload_lds16(Bg1 + k0, BsB + 4096);
    asm volatile("s_waitcnt vmcnt(0)" ::: "memory");
    __syncthreads();

    bf16x8 af[4], bfr[4];
#pragma unroll
    for (int m = 0; m < 4; ++m)
      af[m] = *(const bf16x8*)(As + (wm + m*16 + l15) * 32 + l4 * 8);
#pragma unroll
    for (int n = 0; n < 4; ++n)
      bfr[n] = *(const bf16x8*)(Bs + (wn + n*16 + l15) * 32 + l4 * 8);
#pragma unroll
    for (int m = 0; m < 4; ++m)
#pragma unroll
      for (int n = 0; n < 4; ++n)
        acc[m][n] = __builtin_amdgcn_mfma_f32_16x16x32_bf16(af[m], bfr[n], acc[m][n], 0, 0, 0);
    __syncthreads();
  }

#pragma unroll
  for (int m = 0; m < 4; ++m) {
    const int row = bm + wm + m*16 + l4*4;
#pragma unroll
    for (int n = 0; n < 4; ++n) {
      const int col = bn + wn + n*16 + l15;
#pragma unroll
      for (int r = 0; r < 4; ++r)
        C[(int64_t)(row + r) * N + col] = (OutT)acc[m][n][r];
    }
  }
}

// ---------------- RoPE + scatter ----------------
// Q is pre-scaled by 0.125 * log2(e) so attention can use exp2.
#define QSCALE 0.18033688011112042f
__global__ void rope_scatter(const bf16_t* __restrict__ qkv,
                             const float* __restrict__ cosb, const float* __restrict__ sinb,
                             bf16_t* __restrict__ Q, bf16_t* __restrict__ Kr,
                             bf16_t* __restrict__ Vt) {
  const int row = blockIdx.x;            // b*S + s
  const int b = row / S_, s = row % S_;
  const bf16_t* src = qkv + (int64_t)row * NQKV;
  const float* cs = cosb + s * HD_;
  const float* sn = sinb + s * HD_;
  for (int c = threadIdx.x; c < NQKV; c += 256) {
    if (c < D_) {                        // Q (scaled)
      int h = c >> 6, d = c & 63;
      float v = (float)src[c];
      float p = (d < 32) ? -(float)src[c + 32] : (float)src[c - 32];
      float o = (v * cs[d] + p * sn[d]) * QSCALE;
      Q[((int64_t)(b * H_ + h) * S_ + s) * HD_ + d] = (bf16_t)o;
    } else if (c < D_ + KV_ * HD_) {     // K
      int cc = c - D_;
      int kvh = cc >> 6, d = cc & 63;
      float v = (float)src[c];
      float p = (d < 32) ? -(float)src[c + 32] : (float)src[c - 32];
      float o = v * cs[d] + p * sn[d];
      Kr[((int64_t)(b * KV_ + kvh) * S_ + s) * HD_ + d] = (bf16_t)o;
    } else {                             // V (transposed: [d][s])
      int cc = c - D_ - KV_ * HD_;
      int kvh = cc >> 6, d = cc & 63;
      Vt[((int64_t)(b * KV_ + kvh) * HD_ + d) * S_ + s] = src[c];
    }
  }
}

// ---------------- flash attention, swapped-operand 32x32 MFMA ----------------
// Static exponent shift (softmax is shift-invariant): P = exp2(s - SHIFT).
// No online max, no rescale -> no cross-tile serial dependency.
#define SHIFT_ 8.0f
__global__ __launch_bounds__(256) void attn2(const bf16_t* __restrict__ Q,
                                             const bf16_t* __restrict__ Kr,
                                             const bf16_t* __restrict__ Vt,
                                             bf16_t* __restrict__ AO) {
  const int hb = blockIdx.x;
  const int h = hb & 31, b = hb >> 5;
  const int qc = 15 - blockIdx.y;         // LPT: longest blocks dispatched first
  const int tid = threadIdx.x;
  const int w = tid >> 6, lane = tid & 63;
  const int l31 = lane & 31, hi = lane >> 5;
  const int kvh = h >> 2;                 // NREP = 4
  const int q0w = qc * 128 + w * 32;

  const bf16_t* Qb = Q  + ((int64_t)(b * H_ + h) * S_ + q0w) * HD_;
  const bf16_t* Kb = Kr + (int64_t)(b * KV_ + kvh) * S_ * HD_;
  const bf16_t* Vb = Vt + (int64_t)(b * KV_ + kvh) * HD_ * S_;

  // Q fragments (B-operand): lane holds Q[q = q0w+l31][d = ds*16 + hi*8 + j]
  bf16x8 qf[4];
#pragma unroll
  for (int ds = 0; ds < 4; ++ds)
    qf[ds] = *(const bf16x8*)(Qb + l31 * HD_ + ds * 16 + hi * 8);

  f32x16 accO0 = {}, accO1 = {};          // O^T: rows d (0-31 / 32-63), col q = l31
  float lrun = 0.f;

  const int ND = q0w >> 5;                // tiles 0..ND-1 unmasked, tile ND diagonal

  bf16x8 kf[4];
#pragma unroll
  for (int ds = 0; ds < 4; ++ds)
    kf[ds] = *(const bf16x8*)(Kb + (int64_t)l31 * HD_ + ds * 16 + hi * 8);

  auto tile = [&](int kv0, bool maskdiag, bool prefetch) {
    // S^T[kv][q]: lane(q=l31,hi) holds S[kv=(r&3)+8*(r>>2)+4*hi][q]
    f32x16 sacc = {};
#pragma unroll
    for (int ds = 0; ds < 4; ++ds)
      sacc = __builtin_amdgcn_mfma_f32_32x32x16_bf16(kf[ds], qf[ds], sacc, 0, 0, 0);

    // prefetch next K tile
    if (prefetch) {
#pragma unroll
      for (int ds = 0; ds < 4; ++ds)
        kf[ds] = *(const bf16x8*)(Kb + (int64_t)(kv0 + 32 + l31) * HD_ + ds * 16 + hi * 8);
    }
    // V loads for this tile (needed after softmax)
    bf16x8 v00 = *(const bf16x8*)(Vb + (int64_t)l31 * S_ + kv0 + hi * 8);
    bf16x8 v01 = *(const bf16x8*)(Vb + (int64_t)l31 * S_ + kv0 + 16 + hi * 8);
    bf16x8 v10 = *(const bf16x8*)(Vb + (int64_t)(32 + l31) * S_ + kv0 + hi * 8);
    bf16x8 v11 = *(const bf16x8*)(Vb + (int64_t)(32 + l31) * S_ + kv0 + 16 + hi * 8);

    float p[16];
    float ts = 0.f;
#pragma unroll
    for (int r = 0; r < 16; ++r) {
      float sc = sacc[r];
      if (maskdiag) {
        int kvpos = (r & 3) + 8 * (r >> 2) + 4 * hi;
        if (kvpos > l31) sc = -1e30f;
      }
      p[r] = __builtin_amdgcn_exp2f(sc - SHIFT_);
      ts += p[r];
    }
    ts += __shfl_xor(ts, 32);
    lrun += ts;

    // P -> bf16 B-operand fragments
    u32 pk[8], sh[8];
#pragma unroll
    for (int i = 0; i < 8; ++i) pk[i] = pkbf(p[2*i], p[2*i+1]);
#pragma unroll
    for (int i = 0; i < 8; ++i) sh[i] = __shfl_xor(pk[i], 32);
    u32x4 w0, w1;
    if (hi == 0) {
      w0 = (u32x4){pk[0], pk[1], sh[0], sh[1]};
      w1 = (u32x4){pk[4], pk[5], sh[4], sh[5]};
    } else {
      w0 = (u32x4){sh[2], sh[3], pk[2], pk[3]};
      w1 = (u32x4){sh[6], sh[7], pk[6], pk[7]};
    }
    bf16x8 pf0 = __builtin_bit_cast(bf16x8, w0);
    bf16x8 pf1 = __builtin_bit_cast(bf16x8, w1);

    accO0 = __builtin_amdgcn_mfma_f32_32x32x16_bf16(v00, pf0, accO0, 0, 0, 0);
    accO1 = __builtin_amdgcn_mfma_f32_32x32x16_bf16(v10, pf0, accO1, 0, 0, 0);
    accO0 = __builtin_amdgcn_mfma_f32_32x32x16_bf16(v01, pf1, accO0, 0, 0, 0);
    accO1 = __builtin_amdgcn_mfma_f32_32x32x16_bf16(v11, pf1, accO1, 0, 0, 0);
  };

  for (int t = 0; t < ND; ++t)
    tile(t * 32, false, true);
  tile(ND * 32, true, false);

  // epilogue: lane(q=l31) holds O[q][d], d = dt*32 + (r&3) + 8*(r>>2) + 4*hi
  const float rl = 1.f / lrun;
  const int64_t row = (int64_t)(b * S_ + q0w + l31);
#pragma unroll
  for (int dt = 0; dt < 2; ++dt) {
#pragma unroll
    for (int g = 0; g < 4; ++g) {
      bf16x4 ov;
#pragma unroll
      for (int j = 0; j < 4; ++j) {
        float val = (dt ? accO1[4*g + j] : accO0[4*g + j]) * rl;
        ov[j] = (bf16_t)val;
      }
      const int d0 = dt * 32 + g * 8 + hi * 4;
      *(bf16x4*)(AO + row * D_ + h * HD_ + d0) = ov;
    }
  }
}

// ---------------- launcher ----------------
extern "C" void kernel_launch(void* const* d_in, const int* in_sizes, int n_in,
                              void* d_out, int out_size, void* d_ws, size_t ws_size,
                              hipStream_t stream) {
  const float* x    = (const float*)d_in[0];
  const float* cosb = (const float*)d_in[1];
  const float* sinb = (const float*)d_in[2];
  const float* Wq   = (const float*)d_in[3];
  const float* Wk   = (const float*)d_in[4];
  const float* Wv   = (const float*)d_in[5];
  const float* Wo   = (const float*)d_in[6];
  float* out = (float*)d_out;

  bf16_t* ws = (bf16_t*)d_ws;
  size_t o = 0;
  bf16_t* xb    = ws + o; o += (size_t)4096 * 2048;
  bf16_t* Wqkvt = ws + o; o += (size_t)3072 * 2048;
  bf16_t* Wot   = ws + o; o += (size_t)2048 * 2048;
  bf16_t* qkv   = ws + o; o += (size_t)4096 * 3072;
  bf16_t* Qr    = ws + o; o += (size_t)B_ * H_ * S_ * HD_;
  bf16_t* Krb   = ws + o; o += (size_t)B_ * KV_ * S_ * HD_;
  bf16_t* Vtb   = ws + o; o += (size_t)B_ * KV_ * S_ * HD_;
  bf16_t* AO    = ws + o; o += (size_t)4096 * 2048;

  cvt_f32_bf16<<<(8388608/4 + 255)/256, 256, 0, stream>>>(x, xb, 8388608/4);
  transpose_cvt<<<dim3(2048/32, 2048/32), dim3(32, 8), 0, stream>>>(Wq, Wqkvt, 2048, 0);
  transpose_cvt<<<dim3(512/32, 2048/32),  dim3(32, 8), 0, stream>>>(Wk, Wqkvt, 512, 2048);
  transpose_cvt<<<dim3(512/32, 2048/32),  dim3(32, 8), 0, stream>>>(Wv, Wqkvt, 512, 2560);
  transpose_cvt<<<dim3(2048/32, 2048/32), dim3(32, 8), 0, stream>>>(Wo, Wot, 2048, 0);
  gemm_bt<bf16_t><<<dim3(3072/128, 4096/128), 256, 0, stream>>>(xb, Wqkvt, qkv, 4096, 3072, 2048);
  rope_scatter<<<4096, 256, 0, stream>>>(qkv, cosb, sinb, Qr, Krb, Vtb);
  attn2<<<dim3(64, 16), 256, 0, stream>>>(Qr, Krb, Vtb, AO);
  gemm_bt<float><<<dim3(2048/128, 4096/128), 256, 0, stream>>>(AO, Wot, out, 4096, 2048, 2048);
}

// Round 4
// 281.887 us; speedup vs baseline: 2.2208x; 1.0884x over previous
//
#include <hip/hip_runtime.h>
#include <hip/hip_bf16.h>
#include <stdint.h>

#define B_ 2
#define S_ 2048
#define D_ 2048
#define H_ 32
#define KV_ 8
#define HD_ 64
#define NQKV 3072   // D + 2*KV*HD

typedef __bf16 bf16_t;
typedef __bf16 bf16x8 __attribute__((ext_vector_type(8)));
typedef __bf16 bf16x4 __attribute__((ext_vector_type(4)));
typedef float  f32x4  __attribute__((ext_vector_type(4)));
typedef float  f32x16 __attribute__((ext_vector_type(16)));
typedef unsigned int u32;
typedef u32 u32x4 __attribute__((ext_vector_type(4)));

typedef const __attribute__((address_space(1))) uint32_t* gp1_t;
typedef __attribute__((address_space(3))) uint32_t* lp3_t;

// async global->LDS, 16B per lane. LDS dest is wave-uniform base + lane*16.
__device__ inline void gload_lds16(const void* g, void* l) {
  __builtin_amdgcn_global_load_lds((gp1_t)(uintptr_t)g, (lp3_t)(uint32_t)(uintptr_t)l,
                                   16, 0, 0);
}

__device__ inline u32 pkbf(float a, float b) {
  union { bf16_t h[2]; u32 u; } v;
  v.h[0] = (bf16_t)a; v.h[1] = (bf16_t)b;
  return v.u;
}

// v_permlane32_swap_b32: a = [a_lo, b_lo], b = [a_hi, b_hi]
__device__ inline void pl32swap(u32 &a, u32 &b) {
  asm("v_permlane32_swap_b32 %0, %1" : "+v"(a), "+v"(b));
}

// ---------------- converts ----------------
__global__ void cvt_f32_bf16(const float* __restrict__ in, bf16_t* __restrict__ out, int n4) {
  int i = blockIdx.x * blockDim.x + threadIdx.x;
  if (i < n4) {
    float4 v = ((const float4*)in)[i];
    bf16x4 o;
    o[0] = (bf16_t)v.x; o[1] = (bf16_t)v.y; o[2] = (bf16_t)v.z; o[3] = (bf16_t)v.w;
    ((bf16x4*)out)[i] = o;
  }
}

// transpose + cast: out[row_off + c][r] = in[r][c]
__global__ void transpose_cvt(const float* __restrict__ in, bf16_t* __restrict__ out,
                              int C, int row_off) {
  __shared__ float t[32][33];
  int tx = threadIdx.x, ty = threadIdx.y;       // (32,8)
  int c0 = blockIdx.x * 32, r0 = blockIdx.y * 32;
#pragma unroll
  for (int j = 0; j < 4; ++j)
    t[ty + j*8][tx] = in[(int64_t)(r0 + ty + j*8) * C + c0 + tx];
  __syncthreads();
#pragma unroll
  for (int j = 0; j < 4; ++j)
    out[(int64_t)(row_off + c0 + ty + j*8) * 2048 + r0 + tx] = (bf16_t)t[tx][ty + j*8];
}

// V region of qkv -> Vt[b][kvh][d][s]  (coalesced transposed writes)
__global__ void v_transpose(const bf16_t* __restrict__ qkv, bf16_t* __restrict__ Vt) {
  __shared__ bf16_t t[32][34];
  const int tx = threadIdx.x, ty = threadIdx.y;   // (32,8)
  const int c0 = blockIdx.x * 32;                 // V col within 512
  const int s0 = blockIdx.y * 32;
  const int b  = blockIdx.z;
#pragma unroll
  for (int j = 0; j < 4; ++j)
    t[ty + j*8][tx] = qkv[(int64_t)(b * S_ + s0 + ty + j*8) * NQKV + 2560 + c0 + tx];
  __syncthreads();
#pragma unroll
  for (int j = 0; j < 4; ++j)
    Vt[(int64_t)(b * 512 + c0 + ty + j*8) * S_ + s0 + tx] = t[tx][ty + j*8];
}

// ---------------- GEMM: C = A @ B, with Bt = B^T (N x K) ----------------
template <typename OutT>
__global__ __launch_bounds__(256) void gemm_bt(const bf16_t* __restrict__ A,
                                               const bf16_t* __restrict__ Bt,
                                               OutT* __restrict__ C,
                                               int M, int N, int K) {
  __shared__ bf16_t As[128 * 32];
  __shared__ bf16_t Bs[128 * 32];
  const int tid = threadIdx.x;
  const int wid = tid >> 6, lane = tid & 63;
  const int l15 = lane & 15, l4 = lane >> 4;
  const int bm = blockIdx.y * 128, bn = blockIdx.x * 128;
  const int wm = (wid >> 1) * 64, wn = (wid & 1) * 64;

  f32x4 acc[4][4] = {};

  const int arow0 = tid >> 2;
  const int kslot = (tid & 3) * 8;
  const bf16_t* Ag0 = A  + (int64_t)(bm + arow0)      * K + kslot;
  const bf16_t* Ag1 = A  + (int64_t)(bm + arow0 + 64) * K + kslot;
  const bf16_t* Bg0 = Bt + (int64_t)(bn + arow0)      * K + kslot;
  const bf16_t* Bg1 = Bt + (int64_t)(bn + arow0 + 64) * K + kslot;
  char* AsB = (char*)As + wid * 1024;
  char* BsB = (char*)Bs + wid * 1024;

  for (int k0 = 0; k0 < K; k0 += 32) {
    gload_lds16(Ag0 + k0, AsB);
    gload_lds16(Ag1 + k0, AsB + 4096);
    gload_lds16(Bg0 + k0, BsB);
    gload_lds16(Bg1 + k0, BsB + 4096);
    asm volatile("s_waitcnt vmcnt(0)" ::: "memory");
    __syncthreads();

    bf16x8 af[4], bfr[4];
#pragma unroll
    for (int m = 0; m < 4; ++m)
      af[m] = *(const bf16x8*)(As + (wm + m*16 + l15) * 32 + l4 * 8);
#pragma unroll
    for (int n = 0; n < 4; ++n)
      bfr[n] = *(const bf16x8*)(Bs + (wn + n*16 + l15) * 32 + l4 * 8);
#pragma unroll
    for (int m = 0; m < 4; ++m)
#pragma unroll
      for (int n = 0; n < 4; ++n)
        acc[m][n] = __builtin_amdgcn_mfma_f32_16x16x32_bf16(af[m], bfr[n], acc[m][n], 0, 0, 0);
    __syncthreads();
  }

#pragma unroll
  for (int m = 0; m < 4; ++m) {
    const int row = bm + wm + m*16 + l4*4;
#pragma unroll
    for (int n = 0; n < 4; ++n) {
      const int col = bn + wn + n*16 + l15;
#pragma unroll
      for (int r = 0; r < 4; ++r)
        C[(int64_t)(row + r) * N + col] = (OutT)acc[m][n][r];
    }
  }
}

// ---------------- vectorized RoPE (Q scaled by 0.125*log2e) ----------------
#define QSCALE 0.18033688011112042f
__global__ __launch_bounds__(256) void rope_scatter2(const bf16_t* __restrict__ qkv,
                                                     const float* __restrict__ cosb,
                                                     const float* __restrict__ sinb,
                                                     bf16_t* __restrict__ Q,
                                                     bf16_t* __restrict__ Kr) {
  const int row = blockIdx.x;            // b*S + s
  const int b = row >> 11, s = row & 2047;
  const bf16_t* src = qkv + (int64_t)row * NQKV;
  const float* cs = cosb + s * HD_;
  const float* sn = sinb + s * HD_;
  const int tid = threadIdx.x;
  {                                      // Q: 2048 elems = 256 vectors
    const int c0 = tid * 8;
    const int d0 = c0 & 63, h = c0 >> 6;
    bf16x8 own = *(const bf16x8*)(src + c0);
    bf16x8 par = *(const bf16x8*)(src + (c0 ^ 32));
    const float sgn = (d0 & 32) ? 1.f : -1.f;
    bf16x8 o;
#pragma unroll
    for (int j = 0; j < 8; ++j) {
      const int d = d0 + j;
      float val = (float)own[j] * cs[d] + sgn * (float)par[j] * sn[d];
      o[j] = (bf16_t)(val * QSCALE);
    }
    *(bf16x8*)(Q + ((int64_t)(b * H_ + h) * S_ + s) * HD_ + d0) = o;
  }
  if (tid < 64) {                        // K: 512 elems = 64 vectors
    const int c0 = 2048 + tid * 8;
    const int d0 = (tid * 8) & 63, kvh = tid >> 3;
    bf16x8 own = *(const bf16x8*)(src + c0);
    bf16x8 par = *(const bf16x8*)(src + (c0 ^ 32));
    const float sgn = (d0 & 32) ? 1.f : -1.f;
    bf16x8 o;
#pragma unroll
    for (int j = 0; j < 8; ++j) {
      const int d = d0 + j;
      float val = (float)own[j] * cs[d] + sgn * (float)par[j] * sn[d];
      o[j] = (bf16_t)val;
    }
    *(bf16x8*)(Kr + ((int64_t)(b * KV_ + kvh) * S_ + s) * HD_ + d0) = o;
  }
}

// ---------------- flash attention, paired kv-tiles, permlane P-exchange ----------------
#define SHIFT_ 8.0f
__global__ __launch_bounds__(256) void attn3(const bf16_t* __restrict__ Q,
                                             const bf16_t* __restrict__ Kr,
                                             const bf16_t* __restrict__ Vt,
                                             bf16_t* __restrict__ AO) {
  const int hb = blockIdx.x;
  const int h = hb & 31, b = hb >> 5;
  const int qc = 15 - blockIdx.y;         // LPT: longest blocks first
  const int tid = threadIdx.x;
  const int w = tid >> 6, lane = tid & 63;
  const int l31 = lane & 31, hi = lane >> 5;
  const int kvh = h >> 2;                 // NREP = 4
  const int q0w = qc * 128 + w * 32;

  const bf16_t* Qb = Q  + ((int64_t)(b * H_ + h) * S_ + q0w) * HD_;
  const bf16_t* Kb = Kr + (int64_t)(b * KV_ + kvh) * S_ * HD_;
  const bf16_t* Vb = Vt + (int64_t)(b * KV_ + kvh) * HD_ * S_;

  bf16x8 qf[4];
#pragma unroll
  for (int ds = 0; ds < 4; ++ds)
    qf[ds] = *(const bf16x8*)(Qb + l31 * HD_ + ds * 16 + hi * 8);

  f32x16 accO0 = {}, accO1 = {};          // O^T rows d 0-31 / 32-63, col q = l31
  float lhalf = 0.f;                      // per-half-lane partial denominator
  const int ND = q0w >> 5;

  auto qk = [&](int kv0) -> f32x16 {
    f32x16 s = {};
    __builtin_amdgcn_s_setprio(1);
#pragma unroll
    for (int ds = 0; ds < 4; ++ds) {
      bf16x8 kf = *(const bf16x8*)(Kb + (int64_t)(kv0 + l31) * HD_ + ds * 16 + hi * 8);
      s = __builtin_amdgcn_mfma_f32_32x32x16_bf16(kf, qf[ds], s, 0, 0, 0);
    }
    __builtin_amdgcn_s_setprio(0);
    return s;
  };

  auto softmax_pf = [&](const f32x16 &sacc, bool maskdiag, bf16x8 &pf0, bf16x8 &pf1) {
    float p[16];
#pragma unroll
    for (int r = 0; r < 16; ++r) {
      float sc = sacc[r];
      if (maskdiag) {
        int kvpos = (r & 3) + 8 * (r >> 2) + 4 * hi;
        if (kvpos > l31) sc = -1e30f;
      }
      p[r] = __builtin_amdgcn_exp2f(sc - SHIFT_);
    }
    float t0 = (p[0] + p[1]) + (p[2] + p[3]);
    float t1 = (p[4] + p[5]) + (p[6] + p[7]);
    float t2 = (p[8] + p[9]) + (p[10] + p[11]);
    float t3 = (p[12] + p[13]) + (p[14] + p[15]);
    lhalf += (t0 + t1) + (t2 + t3);
    u32 pk[8];
#pragma unroll
    for (int i = 0; i < 8; ++i) pk[i] = pkbf(p[2*i], p[2*i+1]);
    u32 a0 = pk[0], b0 = pk[2]; pl32swap(a0, b0);
    u32 a1 = pk[1], b1 = pk[3]; pl32swap(a1, b1);
    u32 a2 = pk[4], b2 = pk[6]; pl32swap(a2, b2);
    u32 a3 = pk[5], b3 = pk[7]; pl32swap(a3, b3);
    pf0 = __builtin_bit_cast(bf16x8, (u32x4){a0, a1, b0, b1});
    pf1 = __builtin_bit_cast(bf16x8, (u32x4){a2, a3, b2, b3});
  };

  auto pv = [&](int kv0, bf16x8 pf0, bf16x8 pf1) {
    bf16x8 v00 = *(const bf16x8*)(Vb + (int64_t)l31 * S_ + kv0 + hi * 8);
    bf16x8 v01 = *(const bf16x8*)(Vb + (int64_t)l31 * S_ + kv0 + 16 + hi * 8);
    bf16x8 v10 = *(const bf16x8*)(Vb + (int64_t)(32 + l31) * S_ + kv0 + hi * 8);
    bf16x8 v11 = *(const bf16x8*)(Vb + (int64_t)(32 + l31) * S_ + kv0 + 16 + hi * 8);
    __builtin_amdgcn_s_setprio(1);
    accO0 = __builtin_amdgcn_mfma_f32_32x32x16_bf16(v00, pf0, accO0, 0, 0, 0);
    accO1 = __builtin_amdgcn_mfma_f32_32x32x16_bf16(v10, pf0, accO1, 0, 0, 0);
    accO0 = __builtin_amdgcn_mfma_f32_32x32x16_bf16(v01, pf1, accO0, 0, 0, 0);
    accO1 = __builtin_amdgcn_mfma_f32_32x32x16_bf16(v11, pf1, accO1, 0, 0, 0);
    __builtin_amdgcn_s_setprio(0);
  };

  int t = 0;
  for (; t + 2 <= ND; t += 2) {           // paired tiles: two independent chains
    f32x16 sA = qk(t * 32);
    f32x16 sB = qk(t * 32 + 32);
    bf16x8 pA0, pA1, pB0, pB1;
    softmax_pf(sA, false, pA0, pA1);
    softmax_pf(sB, false, pB0, pB1);
    pv(t * 32, pA0, pA1);
    pv(t * 32 + 32, pB0, pB1);
  }
  if (t < ND) {                           // leftover full tile
    f32x16 sA = qk(t * 32);
    bf16x8 pA0, pA1;
    softmax_pf(sA, false, pA0, pA1);
    pv(t * 32, pA0, pA1);
  }
  {                                       // diagonal tile
    f32x16 sA = qk(ND * 32);
    bf16x8 pA0, pA1;
    softmax_pf(sA, true, pA0, pA1);
    pv(ND * 32, pA0, pA1);
  }

  float lrun = lhalf + __shfl_xor(lhalf, 32);

  const float rl = 1.f / lrun;
  const int64_t row = (int64_t)(b * S_ + q0w + l31);
#pragma unroll
  for (int dt = 0; dt < 2; ++dt) {
#pragma unroll
    for (int g = 0; g < 4; ++g) {
      bf16x4 ov;
#pragma unroll
      for (int j = 0; j < 4; ++j) {
        float val = (dt ? accO1[4*g + j] : accO0[4*g + j]) * rl;
        ov[j] = (bf16_t)val;
      }
      const int d0 = dt * 32 + g * 8 + hi * 4;
      *(bf16x4*)(AO + row * D_ + h * HD_ + d0) = ov;
    }
  }
}

// ---------------- launcher ----------------
extern "C" void kernel_launch(void* const* d_in, const int* in_sizes, int n_in,
                              void* d_out, int out_size, void* d_ws, size_t ws_size,
                              hipStream_t stream) {
  const float* x    = (const float*)d_in[0];
  const float* cosb = (const float*)d_in[1];
  const float* sinb = (const float*)d_in[2];
  const float* Wq   = (const float*)d_in[3];
  const float* Wk   = (const float*)d_in[4];
  const float* Wv   = (const float*)d_in[5];
  const float* Wo   = (const float*)d_in[6];
  float* out = (float*)d_out;

  bf16_t* ws = (bf16_t*)d_ws;
  size_t o = 0;
  bf16_t* xb    = ws + o; o += (size_t)4096 * 2048;
  bf16_t* Wqkvt = ws + o; o += (size_t)3072 * 2048;
  bf16_t* Wot   = ws + o; o += (size_t)2048 * 2048;
  bf16_t* qkv   = ws + o; o += (size_t)4096 * 3072;
  bf16_t* Qr    = ws + o; o += (size_t)B_ * H_ * S_ * HD_;
  bf16_t* Krb   = ws + o; o += (size_t)B_ * KV_ * S_ * HD_;
  bf16_t* Vtb   = ws + o; o += (size_t)B_ * KV_ * S_ * HD_;
  bf16_t* AO    = ws + o; o += (size_t)4096 * 2048;

  cvt_f32_bf16<<<(8388608/4 + 255)/256, 256, 0, stream>>>(x, xb, 8388608/4);
  transpose_cvt<<<dim3(2048/32, 2048/32), dim3(32, 8), 0, stream>>>(Wq, Wqkvt, 2048, 0);
  transpose_cvt<<<dim3(512/32, 2048/32),  dim3(32, 8), 0, stream>>>(Wk, Wqkvt, 512, 2048);
  transpose_cvt<<<dim3(512/32, 2048/32),  dim3(32, 8), 0, stream>>>(Wv, Wqkvt, 512, 2560);
  transpose_cvt<<<dim3(2048/32, 2048/32), dim3(32, 8), 0, stream>>>(Wo, Wot, 2048, 0);
  gemm_bt<bf16_t><<<dim3(3072/128, 4096/128), 256, 0, stream>>>(xb, Wqkvt, qkv, 4096, 3072, 2048);
  rope_scatter2<<<4096, 256, 0, stream>>>(qkv, cosb, sinb, Qr, Krb);
  v_transpose<<<dim3(16, 64, 2), dim3(32, 8), 0, stream>>>(qkv, Vtb);
  attn3<<<dim3(64, 16), 256, 0, stream>>>(Qr, Krb, Vtb, AO);
  gemm_bt<float><<<dim3(2048/128, 4096/128), 256, 0, stream>>>(AO, Wot, out, 4096, 2048, 2048);
}